// Round 16
// baseline (51.391 us; speedup 1.0000x reference)
//
#include <hip/hip_runtime.h>

// B=256, IN_F=512, K_INT=75, OUT_F=64
// ws: Mt2[z][o][k][b] fp32 @ 0 (2 x 4,915,200 B) — K-split slabs. Nothing else.

typedef __attribute__((ext_vector_type(8))) short bf16x8;
typedef __attribute__((ext_vector_type(4))) float f32x4;
typedef unsigned short u16;
typedef unsigned int u32;

__device__ inline u16 f2bf(float f) {            // RNE float->bf16 bits (pair staging)
  u32 u = __float_as_uint(f);
  return (u16)((u + 0x7FFFu + ((u >> 16) & 1u)) >> 16);
}
__device__ inline short bftrunc(float f) {       // truncating cvt (gemm fragments)
  return (short)(__float_as_uint(f) >> 16);
}
__device__ inline float bflo(u32 u) { return __uint_as_float(u << 16); }
__device__ inline float bfhi(u32 u) { return __uint_as_float(u & 0xFFFF0000u); }

// ---------- MFMA GEMM from raw fp32 inputs (R15 body + XCD-swizzled 1D grid) ----------
// Grid 608: id = y*152 + (kc*2+z); 152%8==0 -> all 4 y-blocks of one (kc,z) share an XCD.
__global__ __launch_bounds__(256) void md_gemm_direct(const float* __restrict__ x,
                                                      const float* __restrict__ T,
                                                      float* __restrict__ Mt2) {
  const int id = blockIdx.x;
  const int y = id / 152;                  // b-tile 0..3
  const int rem = id - y * 152;            // 0..151
  if (rem >= 150) return;                  // 8 dead blocks
  const int kc = rem >> 1;                 // 0..74
  const int z = rem & 1;                   // K-half

  const int tid = threadIdx.x;
  const int l = tid & 63, w = tid >> 6;
  const int b0 = (y << 6) + ((w & 1) << 5);
  const int lr = l & 15;
  const int ko = (l >> 4) << 3;            // 8 contiguous f per lane group
  const int oh = (w >> 1) << 5;            // o-half base 0/32

  const float* At = T + (z * 256 + ko) * 4800 + kc * 64 + oh + lr;
  const float* Bx0 = x + (b0 + lr) * 512 + z * 256 + ko;
  const float* Bx1 = Bx0 + 16 * 512;

  f32x4 d00 = {0.f, 0.f, 0.f, 0.f}, d01 = d00, d10 = d00, d11 = d00;

#pragma unroll 2
  for (int kk = 0; kk < 8; ++kk) {
    bf16x8 a0, a1, f0, f1;
    const float* Ak = At + (kk << 5) * 4800;
#pragma unroll
    for (int e = 0; e < 8; ++e) {
      a0[e] = bftrunc(Ak[e * 4800]);         // o = oh+lr
      a1[e] = bftrunc(Ak[e * 4800 + 16]);    // o = oh+lr+16
    }
    const float4 b00 = *reinterpret_cast<const float4*>(Bx0 + (kk << 5));
    const float4 b01 = *reinterpret_cast<const float4*>(Bx0 + (kk << 5) + 4);
    const float4 b10 = *reinterpret_cast<const float4*>(Bx1 + (kk << 5));
    const float4 b11 = *reinterpret_cast<const float4*>(Bx1 + (kk << 5) + 4);
    f0[0] = bftrunc(b00.x); f0[1] = bftrunc(b00.y); f0[2] = bftrunc(b00.z); f0[3] = bftrunc(b00.w);
    f0[4] = bftrunc(b01.x); f0[5] = bftrunc(b01.y); f0[6] = bftrunc(b01.z); f0[7] = bftrunc(b01.w);
    f1[0] = bftrunc(b10.x); f1[1] = bftrunc(b10.y); f1[2] = bftrunc(b10.z); f1[3] = bftrunc(b10.w);
    f1[4] = bftrunc(b11.x); f1[5] = bftrunc(b11.y); f1[6] = bftrunc(b11.z); f1[7] = bftrunc(b11.w);

    d00 = __builtin_amdgcn_mfma_f32_16x16x32_bf16(a0, f0, d00, 0, 0, 0);
    d01 = __builtin_amdgcn_mfma_f32_16x16x32_bf16(a0, f1, d01, 0, 0, 0);
    d10 = __builtin_amdgcn_mfma_f32_16x16x32_bf16(a1, f0, d10, 0, 0, 0);
    d11 = __builtin_amdgcn_mfma_f32_16x16x32_bf16(a1, f1, d11, 0, 0, 0);
  }

  float* Mt = Mt2 + z * 1228800;
  const int n0 = (kc << 6) + oh;
#pragma unroll
  for (int r = 0; r < 4; ++r) {
    const int row = ((l >> 4) << 2) + r;
    {
      const int n = n0 + row;
      float* base = Mt + (n & 63) * 19200 + (n >> 6) * 256;
      base[b0 + lr] = d00[r];
      base[b0 + 16 + lr] = d01[r];
    }
    {
      const int n = n0 + 16 + row;
      float* base = Mt + (n & 63) * 19200 + (n >> 6) * 256;
      base[b0 + lr] = d10[r];
      base[b0 + 16 + lr] = d11[r];
    }
  }
}

// ---------- pairwise v5: single full-K stage (bf16 j-panel 75x256 + f32 i-panel) ----------
// 512 thr: is=tid&15 (2 i), jg=tid>>4 (8 j). One barrier round; fixed 75-iter loop.
__global__ __launch_bounds__(512) void md_pair5(const float* __restrict__ Mt2,
                                                float* __restrict__ out) {
  const int bid = blockIdx.x;
  const int o = bid & 63;
  const int it = bid >> 6;             // 0..7
  const int ibase = it << 5;           // 32 i per block
  const int tid = threadIdx.x;
  const int is = tid & 15;             // i-slot (2 i's)
  const int jg = tid >> 4;             // j-group (8 j's), 0..31

  __shared__ alignas(16) u16 MjB[75 * 256];    // 38,400 B  bf16 j-panel (full K)
  __shared__ alignas(16) float MiF[75 * 32];   //  9,600 B  f32 i-panel

  const float* M0 = Mt2 + o * 19200;           // slab 0
  const float* M1 = M0 + 1228800;              // slab 1

  // stage j-panel: 4800 uint2 writes, global reads coalesced float4
  for (int idx = tid; idx < 75 * 64; idx += 512) {
    const int kk = idx >> 6, q = idx & 63;
    const int goff = kk * 256 + (q << 2);
    const float4 v0 = *reinterpret_cast<const float4*>(M0 + goff);
    const float4 v1 = *reinterpret_cast<const float4*>(M1 + goff);
    uint2 p;
    p.x = (u32)f2bf(v0.x + v1.x) | ((u32)f2bf(v0.y + v1.y) << 16);
    p.y = (u32)f2bf(v0.z + v1.z) | ((u32)f2bf(v0.w + v1.w) << 16);
    *reinterpret_cast<uint2*>(MjB + kk * 256 + (q << 2)) = p;
  }
  // stage i-panel: 2400 f32 writes
  for (int idx = tid; idx < 75 * 32; idx += 512) {
    const int kk = idx >> 5, ii = idx & 31;
    const int goff = kk * 256 + ibase + ii;
    MiF[kk * 32 + ii] = M0[goff] + M1[goff];
  }
  __syncthreads();

  float d[2][8];
#pragma unroll
  for (int a = 0; a < 2; ++a)
#pragma unroll
    for (int b = 0; b < 8; ++b) d[a][b] = 0.0f;

#pragma unroll 15
  for (int kk = 0; kk < 75; ++kk) {
    const float2 vi = *reinterpret_cast<const float2*>(MiF + kk * 32 + (is << 1));
    const uint4 ju = *reinterpret_cast<const uint4*>(MjB + kk * 256 + (jg << 3));
    const float ja[8] = {bflo(ju.x), bfhi(ju.x), bflo(ju.y), bfhi(ju.y),
                         bflo(ju.z), bfhi(ju.z), bflo(ju.w), bfhi(ju.w)};
#pragma unroll
    for (int b = 0; b < 8; ++b) {
      d[0][b] += __builtin_fabsf(ja[b] - vi.x);
      d[1][b] += __builtin_fabsf(ja[b] - vi.y);
    }
  }

  float s[2];
#pragma unroll
  for (int a = 0; a < 2; ++a) {
    const int ia = ibase + (is << 1) + a;
    float t = 0.0f;
#pragma unroll
    for (int b = 0; b < 8; ++b) {
      const int j = (jg << 3) + b;
      const float e = __expf(-d[a][b]);
      t += (j == ia) ? 0.0f : e;               // skip self-term exactly
    }
    s[a] = t;
  }

  __syncthreads();                     // panel reads done; overlay reduce scratch
  float* red = reinterpret_cast<float*>(MjB);  // red[i_local 32][jg 32], stride 33
  red[((is << 1) + 0) * 33 + jg] = s[0];
  red[((is << 1) + 1) * 33 + jg] = s[1];
  __syncthreads();
  if (tid < 32) {
    float t = 0.0f;
#pragma unroll
    for (int g = 0; g < 32; ++g) t += red[tid * 33 + g];
    out[(ibase + tid) * 64 + o] = t;           // self-term already excluded
  }
}

extern "C" void kernel_launch(void* const* d_in, const int* in_sizes, int n_in,
                              void* d_out, int out_size, void* d_ws, size_t ws_size,
                              hipStream_t stream) {
  const float* x = (const float*)d_in[0];   // [256,512]
  const float* T = (const float*)d_in[1];   // [512,75,64]
  float* out = (float*)d_out;               // [256,64]

  float* Mt2 = (float*)d_ws;                // 2 x 4,915,200 B

  md_gemm_direct<<<608, 256, 0, stream>>>(x, T, Mt2);
  md_pair5<<<512, 512, 0, stream>>>(Mt2, out);
}

// Round 17
// 50.154 us; speedup vs baseline: 1.0247x; 1.0247x over previous
//
#include <hip/hip_runtime.h>

// B=256, IN_F=512, K_INT=75, OUT_F=64
// ws: Mt2[z][o][k][b] fp32 @ 0 (2 x 4,915,200 B) — K-split slabs. Nothing else.

typedef __attribute__((ext_vector_type(8))) short bf16x8;
typedef __attribute__((ext_vector_type(4))) float f32x4;
typedef unsigned short u16;
typedef unsigned int u32;

__device__ inline u16 f2bf(float f) {            // RNE float->bf16 bits (pair staging)
  u32 u = __float_as_uint(f);
  return (u16)((u + 0x7FFFu + ((u >> 16) & 1u)) >> 16);
}
__device__ inline short bftrunc(float f) {       // truncating cvt (gemm fragments)
  return (short)(__float_as_uint(f) >> 16);
}
__device__ inline float bflo(u32 u) { return __uint_as_float(u << 16); }
__device__ inline float bfhi(u32 u) { return __uint_as_float(u & 0xFFFF0000u); }

// ---------- MFMA GEMM from raw fp32 inputs (verbatim R15) ----------
__global__ __launch_bounds__(256) void md_gemm_direct(const float* __restrict__ x,
                                                      const float* __restrict__ T,
                                                      float* __restrict__ Mt2) {
  const int tid = threadIdx.x;
  const int l = tid & 63, w = tid >> 6;
  const int bx = blockIdx.x;               // kc 0..74
  const int b0 = (blockIdx.y << 6) + ((w & 1) << 5);
  const int z = blockIdx.z;                // K-half: f in [z*256, z*256+256)
  const int lr = l & 15;
  const int ko = (l >> 4) << 3;            // 8 contiguous f per lane group
  const int oh = (w >> 1) << 5;            // o-half base 0/32

  const float* At = T + (z * 256 + ko) * 4800 + bx * 64 + oh + lr;
  const float* Bx0 = x + (b0 + lr) * 512 + z * 256 + ko;
  const float* Bx1 = Bx0 + 16 * 512;

  f32x4 d00 = {0.f, 0.f, 0.f, 0.f}, d01 = d00, d10 = d00, d11 = d00;

#pragma unroll 2
  for (int kk = 0; kk < 8; ++kk) {
    bf16x8 a0, a1, f0, f1;
    const float* Ak = At + (kk << 5) * 4800;
#pragma unroll
    for (int e = 0; e < 8; ++e) {
      a0[e] = bftrunc(Ak[e * 4800]);         // o = oh+lr
      a1[e] = bftrunc(Ak[e * 4800 + 16]);    // o = oh+lr+16
    }
    const float4 b00 = *reinterpret_cast<const float4*>(Bx0 + (kk << 5));
    const float4 b01 = *reinterpret_cast<const float4*>(Bx0 + (kk << 5) + 4);
    const float4 b10 = *reinterpret_cast<const float4*>(Bx1 + (kk << 5));
    const float4 b11 = *reinterpret_cast<const float4*>(Bx1 + (kk << 5) + 4);
    f0[0] = bftrunc(b00.x); f0[1] = bftrunc(b00.y); f0[2] = bftrunc(b00.z); f0[3] = bftrunc(b00.w);
    f0[4] = bftrunc(b01.x); f0[5] = bftrunc(b01.y); f0[6] = bftrunc(b01.z); f0[7] = bftrunc(b01.w);
    f1[0] = bftrunc(b10.x); f1[1] = bftrunc(b10.y); f1[2] = bftrunc(b10.z); f1[3] = bftrunc(b10.w);
    f1[4] = bftrunc(b11.x); f1[5] = bftrunc(b11.y); f1[6] = bftrunc(b11.z); f1[7] = bftrunc(b11.w);

    d00 = __builtin_amdgcn_mfma_f32_16x16x32_bf16(a0, f0, d00, 0, 0, 0);
    d01 = __builtin_amdgcn_mfma_f32_16x16x32_bf16(a0, f1, d01, 0, 0, 0);
    d10 = __builtin_amdgcn_mfma_f32_16x16x32_bf16(a1, f0, d10, 0, 0, 0);
    d11 = __builtin_amdgcn_mfma_f32_16x16x32_bf16(a1, f1, d11, 0, 0, 0);
  }

  float* Mt = Mt2 + z * 1228800;
  const int n0 = (bx << 6) + oh;
#pragma unroll
  for (int r = 0; r < 4; ++r) {
    const int row = ((l >> 4) << 2) + r;
    {
      const int n = n0 + row;
      float* base = Mt + (n & 63) * 19200 + (n >> 6) * 256;
      base[b0 + lr] = d00[r];
      base[b0 + 16 + lr] = d01[r];
    }
    {
      const int n = n0 + 16 + row;
      float* base = Mt + (n & 63) * 19200 + (n >> 6) * 256;
      base[b0 + lr] = d10[r];
      base[b0 + 16 + lr] = d11[r];
    }
  }
}

// ---------- symmetric pairwise: 64x64 (i,j) tile per block, bf16 panels, atomic out ----------
// Grid 640 = tp*64 + o (bid%8 = o%8 -> same-o blocks on one XCD). 256 thr: 2i x 8j.
// Self-term skipped in-register; diag blocks write i-sums only. Requires out pre-zeroed.
#define PSTR 72   // u16 row stride: 144 B (16B-aligned rows), read banks conflict-free
__global__ __launch_bounds__(256) void md_pair_sym(const float* __restrict__ Mt2,
                                                   float* __restrict__ out) {
  const int bid = blockIdx.x;
  const int o = bid & 63;
  const int tp = bid >> 6;                 // 0..9
  const int TI[10] = {0, 0, 0, 0, 1, 1, 1, 2, 2, 3};
  const int TJ[10] = {0, 1, 2, 3, 1, 2, 3, 2, 3, 3};
  const int ti = TI[tp], tj = TJ[tp];
  const bool diag = (ti == tj);
  const int tid = threadIdx.x;

  __shared__ alignas(16) u16 panel[2][75 * PSTR];   // 21,600 B
  u16* Mi = panel[0];
  u16* Mj = diag ? panel[0] : panel[1];

  const float* M0 = Mt2 + o * 19200;       // slab 0
  const float* M1 = M0 + 1228800;          // slab 1

  // stage panels: 75 rows x 16 float4 per panel (sum slabs, cvt bf16)
  for (int idx = tid; idx < 1200; idx += 256) {
    const int kk = idx >> 4, q = idx & 15;
    {
      const int goff = kk * 256 + (ti << 6) + (q << 2);
      const float4 v0 = *reinterpret_cast<const float4*>(M0 + goff);
      const float4 v1 = *reinterpret_cast<const float4*>(M1 + goff);
      uint2 p;
      p.x = (u32)f2bf(v0.x + v1.x) | ((u32)f2bf(v0.y + v1.y) << 16);
      p.y = (u32)f2bf(v0.z + v1.z) | ((u32)f2bf(v0.w + v1.w) << 16);
      *reinterpret_cast<uint2*>(Mi + kk * PSTR + (q << 2)) = p;
    }
    if (!diag) {
      const int goff = kk * 256 + (tj << 6) + (q << 2);
      const float4 v0 = *reinterpret_cast<const float4*>(M0 + goff);
      const float4 v1 = *reinterpret_cast<const float4*>(M1 + goff);
      uint2 p;
      p.x = (u32)f2bf(v0.x + v1.x) | ((u32)f2bf(v0.y + v1.y) << 16);
      p.y = (u32)f2bf(v0.z + v1.z) | ((u32)f2bf(v0.w + v1.w) << 16);
      *reinterpret_cast<uint2*>(Mj + kk * PSTR + (q << 2)) = p;
    }
  }
  __syncthreads();

  const int is = tid & 31;                 // i_local = 2*is + a
  const int jg = tid >> 5;                 // j_local = 8*jg + b

  float d[2][8];
#pragma unroll
  for (int a = 0; a < 2; ++a)
#pragma unroll
    for (int b = 0; b < 8; ++b) d[a][b] = 0.0f;

#pragma unroll 15
  for (int kk = 0; kk < 75; ++kk) {
    const u32 vi = *reinterpret_cast<const u32*>(Mi + kk * PSTR + (is << 1));  // 32 addrs: free
    const uint4 ju = *reinterpret_cast<const uint4*>(Mj + kk * PSTR + (jg << 3)); // 8 addrs: bcast
    const float i0 = bflo(vi), i1 = bfhi(vi);
    const float ja[8] = {bflo(ju.x), bfhi(ju.x), bflo(ju.y), bfhi(ju.y),
                         bflo(ju.z), bfhi(ju.z), bflo(ju.w), bfhi(ju.w)};
#pragma unroll
    for (int b = 0; b < 8; ++b) {
      d[0][b] += __builtin_fabsf(ja[b] - i0);
      d[1][b] += __builtin_fabsf(ja[b] - i1);
    }
  }

  float isum[2] = {0.0f, 0.0f};
  float jsum[8] = {0.f, 0.f, 0.f, 0.f, 0.f, 0.f, 0.f, 0.f};
#pragma unroll
  for (int a = 0; a < 2; ++a) {
    const int gi = (ti << 6) + (is << 1) + a;
#pragma unroll
    for (int b = 0; b < 8; ++b) {
      const int gj = (tj << 6) + (jg << 3) + b;
      const float e = __expf(-d[a][b]);
      if (gi != gj) { isum[a] += e; jsum[b] += e; }   // self-cell excluded exactly
    }
  }

  // i-side reduce (sum over 8 jg) -> atomicAdd rows of group ti
  __syncthreads();                         // panel reads done; overlay scratch
  float* red = reinterpret_cast<float*>(panel);      // [64][33] = 8448 B
  red[((is << 1) + 0) * 33 + jg] = isum[0];
  red[((is << 1) + 1) * 33 + jg] = isum[1];
  __syncthreads();
  if (tid < 64) {
    float t = 0.0f;
#pragma unroll
    for (int g = 0; g < 8; ++g) t += red[tid * 33 + g];
    atomicAdd(&out[((ti << 6) + tid) * 64 + o], t);
  }

  // j-side reduce (sum over 32 is) -> atomicAdd rows of group tj (off-diag only)
  if (!diag) {
    __syncthreads();
#pragma unroll
    for (int b = 0; b < 8; ++b) red[((jg << 3) + b) * 33 + is] = jsum[b];
    __syncthreads();
    if (tid < 64) {
      float t = 0.0f;
#pragma unroll
      for (int g = 0; g < 32; ++g) t += red[tid * 33 + g];
      atomicAdd(&out[((tj << 6) + tid) * 64 + o], t);
    }
  }
}

extern "C" void kernel_launch(void* const* d_in, const int* in_sizes, int n_in,
                              void* d_out, int out_size, void* d_ws, size_t ws_size,
                              hipStream_t stream) {
  const float* x = (const float*)d_in[0];   // [256,512]
  const float* T = (const float*)d_in[1];   // [512,75,64]
  float* out = (float*)d_out;               // [256,64]

  float* Mt2 = (float*)d_ws;                // 2 x 4,915,200 B

  hipMemsetAsync(out, 0, 256 * 64 * sizeof(float), stream);  // atomics accumulate into 0
  md_gemm_direct<<<dim3(75, 4, 2), 256, 0, stream>>>(x, T, Mt2);
  md_pair_sym<<<640, 256, 0, stream>>>(Mt2, out);
}

// Round 18
// 49.534 us; speedup vs baseline: 1.0375x; 1.0125x over previous
//
#include <hip/hip_runtime.h>

// B=256, IN_F=512, K_INT=75, OUT_F=64
// ws: Mt2[z][o][k][b] fp32 @ 0 (2 x 4,915,200 B) — K-split slabs. Nothing else.

typedef __attribute__((ext_vector_type(8))) short bf16x8;
typedef __attribute__((ext_vector_type(4))) float f32x4;
typedef unsigned short u16;
typedef unsigned int u32;

__device__ inline u16 f2bf(float f) {            // RNE float->bf16 bits (pair staging)
  u32 u = __float_as_uint(f);
  return (u16)((u + 0x7FFFu + ((u >> 16) & 1u)) >> 16);
}
__device__ inline short bftrunc(float f) {       // truncating cvt (gemm fragments)
  return (short)(__float_as_uint(f) >> 16);
}
__device__ inline float bflo(u32 u) { return __uint_as_float(u << 16); }
__device__ inline float bfhi(u32 u) { return __uint_as_float(u & 0xFFFF0000u); }

// ---------- MFMA GEMM from raw fp32 inputs (verbatim R15, session-best) ----------
__global__ __launch_bounds__(256) void md_gemm_direct(const float* __restrict__ x,
                                                      const float* __restrict__ T,
                                                      float* __restrict__ Mt2) {
  const int tid = threadIdx.x;
  const int l = tid & 63, w = tid >> 6;
  const int bx = blockIdx.x;               // kc 0..74
  const int b0 = (blockIdx.y << 6) + ((w & 1) << 5);
  const int z = blockIdx.z;                // K-half: f in [z*256, z*256+256)
  const int lr = l & 15;
  const int ko = (l >> 4) << 3;            // 8 contiguous f per lane group
  const int oh = (w >> 1) << 5;            // o-half base 0/32

  const float* At = T + (z * 256 + ko) * 4800 + bx * 64 + oh + lr;
  const float* Bx0 = x + (b0 + lr) * 512 + z * 256 + ko;
  const float* Bx1 = Bx0 + 16 * 512;

  f32x4 d00 = {0.f, 0.f, 0.f, 0.f}, d01 = d00, d10 = d00, d11 = d00;

#pragma unroll 2
  for (int kk = 0; kk < 8; ++kk) {
    bf16x8 a0, a1, f0, f1;
    const float* Ak = At + (kk << 5) * 4800;
#pragma unroll
    for (int e = 0; e < 8; ++e) {
      a0[e] = bftrunc(Ak[e * 4800]);         // o = oh+lr
      a1[e] = bftrunc(Ak[e * 4800 + 16]);    // o = oh+lr+16
    }
    const float4 b00 = *reinterpret_cast<const float4*>(Bx0 + (kk << 5));
    const float4 b01 = *reinterpret_cast<const float4*>(Bx0 + (kk << 5) + 4);
    const float4 b10 = *reinterpret_cast<const float4*>(Bx1 + (kk << 5));
    const float4 b11 = *reinterpret_cast<const float4*>(Bx1 + (kk << 5) + 4);
    f0[0] = bftrunc(b00.x); f0[1] = bftrunc(b00.y); f0[2] = bftrunc(b00.z); f0[3] = bftrunc(b00.w);
    f0[4] = bftrunc(b01.x); f0[5] = bftrunc(b01.y); f0[6] = bftrunc(b01.z); f0[7] = bftrunc(b01.w);
    f1[0] = bftrunc(b10.x); f1[1] = bftrunc(b10.y); f1[2] = bftrunc(b10.z); f1[3] = bftrunc(b10.w);
    f1[4] = bftrunc(b11.x); f1[5] = bftrunc(b11.y); f1[6] = bftrunc(b11.z); f1[7] = bftrunc(b11.w);

    d00 = __builtin_amdgcn_mfma_f32_16x16x32_bf16(a0, f0, d00, 0, 0, 0);
    d01 = __builtin_amdgcn_mfma_f32_16x16x32_bf16(a0, f1, d01, 0, 0, 0);
    d10 = __builtin_amdgcn_mfma_f32_16x16x32_bf16(a1, f0, d10, 0, 0, 0);
    d11 = __builtin_amdgcn_mfma_f32_16x16x32_bf16(a1, f1, d11, 0, 0, 0);
  }

  float* Mt = Mt2 + z * 1228800;
  const int n0 = (bx << 6) + oh;
#pragma unroll
  for (int r = 0; r < 4; ++r) {
    const int row = ((l >> 4) << 2) + r;
    {
      const int n = n0 + row;
      float* base = Mt + (n & 63) * 19200 + (n >> 6) * 256;
      base[b0 + lr] = d00[r];
      base[b0 + 16 + lr] = d01[r];
    }
    {
      const int n = n0 + 16 + row;
      float* base = Mt + (n & 63) * 19200 + (n >> 6) * 256;
      base[b0 + lr] = d10[r];
      base[b0 + 16 + lr] = d11[r];
    }
  }
}

// ---------- symmetric pairwise, half-tiles: 32i x 64j per block, 20 waves/CU ----------
// Grid 1280 = piece*64 + o; piece = tp*2 + h (tp 0..9 from TI/TJ, h = which 32-row half).
// 256 thr: il=tid&31 (1 i), jg=tid>>5 (8 j). i-panel f32 (no unpack), j-panel bf16.
// Diag pieces: isum only (all cells explicit). Off-diag: isum + partial jsum.
// All output via atomicAdd into pre-zeroed out; self-term skipped in-register.
#define JSTR 72   // u16 j-row stride: 144 B, 16B-aligned
#define ISTR 36   // f32 i-row stride: 144 B, 16B-aligned, conflict-free b32 reads
__global__ __launch_bounds__(256) void md_pair_sym2(const float* __restrict__ Mt2,
                                                    float* __restrict__ out) {
  const int bid = blockIdx.x;
  const int o = bid & 63;
  const int p = bid >> 6;                  // 0..19
  const int tp = p >> 1, h = p & 1;
  const int TI[10] = {0, 0, 0, 0, 1, 1, 1, 2, 2, 3};
  const int TJ[10] = {0, 1, 2, 3, 1, 2, 3, 2, 3, 3};
  const int ti = TI[tp], tj = TJ[tp];
  const bool diag = (ti == tj);
  const int irow0 = (ti << 6) + (h << 5);  // this piece's 32 i rows
  const int tid = threadIdx.x;

  __shared__ alignas(16) u16 Pj[75 * JSTR];    // 10,800 B  bf16 j-panel (64 cols)
  __shared__ alignas(16) float Pi[75 * ISTR];  // 10,800 B  f32  i-panel (32 cols)

  const float* M0 = Mt2 + o * 19200;           // slab 0
  const float* M1 = M0 + 1228800;              // slab 1

  // stage j-panel: 75 k-rows x 16 quads (sum slabs, cvt bf16)
  for (int idx = tid; idx < 1200; idx += 256) {
    const int kk = idx >> 4, q = idx & 15;
    const int goff = kk * 256 + (tj << 6) + (q << 2);
    const float4 v0 = *reinterpret_cast<const float4*>(M0 + goff);
    const float4 v1 = *reinterpret_cast<const float4*>(M1 + goff);
    uint2 pk;
    pk.x = (u32)f2bf(v0.x + v1.x) | ((u32)f2bf(v0.y + v1.y) << 16);
    pk.y = (u32)f2bf(v0.z + v1.z) | ((u32)f2bf(v0.w + v1.w) << 16);
    *reinterpret_cast<uint2*>(Pj + kk * JSTR + (q << 2)) = pk;
  }
  // stage i-panel: 75 k-rows x 32 f32 (sum slabs, keep f32)
  for (int idx = tid; idx < 2400; idx += 256) {
    const int kk = idx >> 5, ii = idx & 31;
    const int goff = kk * 256 + irow0 + ii;
    Pi[kk * ISTR + ii] = M0[goff] + M1[goff];
  }
  __syncthreads();

  const int il = tid & 31;                 // i_local 0..31
  const int jg = tid >> 5;                 // j-octet 0..7

  float d[8];
#pragma unroll
  for (int b = 0; b < 8; ++b) d[b] = 0.0f;

#pragma unroll 15
  for (int kk = 0; kk < 75; ++kk) {
    const float vi = Pi[kk * ISTR + il];                                  // 32 dwords: free
    const uint4 ju = *reinterpret_cast<const uint4*>(Pj + kk * JSTR + (jg << 3)); // bcast
    const float ja[8] = {bflo(ju.x), bfhi(ju.x), bflo(ju.y), bfhi(ju.y),
                         bflo(ju.z), bfhi(ju.z), bflo(ju.w), bfhi(ju.w)};
#pragma unroll
    for (int b = 0; b < 8; ++b) d[b] += __builtin_fabsf(ja[b] - vi);
  }

  float isum = 0.0f;
  float jsum[8] = {0.f, 0.f, 0.f, 0.f, 0.f, 0.f, 0.f, 0.f};
  const int gi = irow0 + il;
#pragma unroll
  for (int b = 0; b < 8; ++b) {
    const int gj = (tj << 6) + (jg << 3) + b;
    const float e = __expf(-d[b]);
    if (gi != gj) { isum += e; jsum[b] += e; }   // self-cell excluded exactly
  }

  // i-side: reduce isum over 8 jg -> atomicAdd 32 rows
  __syncthreads();                         // panel reads done; overlay scratch
  float* red = reinterpret_cast<float*>(Pj);         // [32][9] = 1152 B
  red[il * 9 + jg] = isum;
  __syncthreads();
  if (tid < 32) {
    float t = 0.0f;
#pragma unroll
    for (int g = 0; g < 8; ++g) t += red[tid * 9 + g];
    atomicAdd(&out[(irow0 + tid) * 64 + o], t);
  }

  // j-side (off-diag only): reduce jsum over 32 il -> atomicAdd 64 cols (partial)
  if (!diag) {
    __syncthreads();
    float* red2 = reinterpret_cast<float*>(Pi);      // [64][33] = 8448 B
#pragma unroll
    for (int b = 0; b < 8; ++b) red2[((jg << 3) + b) * 33 + il] = jsum[b];
    __syncthreads();
    if (tid < 64) {
      float t = 0.0f;
#pragma unroll
      for (int g = 0; g < 32; ++g) t += red2[tid * 33 + g];
      atomicAdd(&out[((tj << 6) + tid) * 64 + o], t);
    }
  }
}

extern "C" void kernel_launch(void* const* d_in, const int* in_sizes, int n_in,
                              void* d_out, int out_size, void* d_ws, size_t ws_size,
                              hipStream_t stream) {
  const float* x = (const float*)d_in[0];   // [256,512]
  const float* T = (const float*)d_in[1];   // [512,75,64]
  float* out = (float*)d_out;               // [256,64]

  float* Mt2 = (float*)d_ws;                // 2 x 4,915,200 B

  hipMemsetAsync(out, 0, 256 * 64 * sizeof(float), stream);  // atomics accumulate into 0
  md_gemm_direct<<<dim3(75, 4, 2), 256, 0, stream>>>(x, T, Mt2);
  md_pair_sym2<<<1280, 256, 0, stream>>>(Mt2, out);
}